// Round 11
// baseline (1314.703 us; speedup 1.0000x reference)
//
#include <hip/hip_runtime.h>

// ForexLSTM: 2-layer LSTM (B=1024, T=512, D=14, H=128) + batchnorm-over-batch + MLP(128->32->1)
//
// Round 21: back to R12 (the ONLY shape measured at VGPR 256 / zero scratch; 964.7us)
// + top-of-phase LDS fragment prefetch. The allocator fight is over: four mechanisms
// (launch_bounds, waves_per_eu, num_vgpr, keep-alive pins) all failed to lift the
// redistributed-epilogue builds off the 128-VGPR clamp; R16-at-948 == R12-at-964
// because spill refills ate the redistribution's VALU win. R12's residual ~21% idle
// is lgkmcnt exposure: 17 ds_read_b128/wave/phase issued one-at-a-time inside the
// kt loops, each cluster's first MFMA eating ~120cy LDS latency with only 2 waves/SIMD.
//   - Hoist the 9 state-fragment reads (bx, h1f kt0-3, h2f kt0-3 = 36 VGPRs) to named
//     locals right after the barrier, before any MFMA: compiler emits them back-to-back
//     and places fine-grained lgkmcnt(N) waits, streaming the LDS pipe under the MFMA
//     window. whh1lds reads stay inline (hoisting them would overpressure the budget).
//   - No sync-structure change, no cross-wave reordering (R13 raced), epilogues stay
//     R12-fat 4-cellP (the shape that keeps the allocator at 256).
//   - Everything else R12-exact: wave-role merge, shared h1f feeds both layers,
//     Whh1 kt0-1 regs / kt2-3 LDS (82 KB), fused-reciprocal cellP (5 exp2 + 2 rcp),
//     incremental x prefetch, __launch_bounds__(NT, 1).

#define B_ 1024
#define T_ 512
#define D_ 14
#define H_ 128
#define NB 4
#define NT 512

#define L2E 1.44269504088896f
#define L2E2 2.88539008177793f

typedef _Float16 f16;
typedef _Float16 half4 __attribute__((ext_vector_type(4)));
typedef _Float16 half8 __attribute__((ext_vector_type(8)));
typedef _Float16 f16x2 __attribute__((ext_vector_type(2)));
typedef float floatx4 __attribute__((ext_vector_type(4)));

__device__ __forceinline__ half8 ldfrag_s(const float* __restrict__ p, float s) {
    half8 r;
#pragma unroll
    for (int j = 0; j < 8; ++j) r[j] = (f16)(p[j] * s);
    return r;
}

#define MFMA(a, b, c) __builtin_amdgcn_mfma_f32_16x16x32_f16((a), (b), (c), 0, 0, 0)

// Fused LSTM cell epilogue on pre-scaled gates:
//   pi,pf,po = y*log2e ; pg = 2x*log2e ; cs = 2*log2e*c (scaled cell state, updated).
// Returns h in true units. 5 exp2 + 2 rcp.
__device__ __forceinline__ float cellP(float pi, float pf, float pg, float po, float& cs)
{
    float a = __builtin_amdgcn_exp2f(-pi);
    float u = __builtin_amdgcn_exp2f(-pf);
    float b = __builtin_amdgcn_exp2f(pg);
    float d = __builtin_amdgcn_exp2f(-po);
    float t1 = 1.0f + a;
    float t3 = 1.0f + u;
    float t2 = __builtin_fmaf(t1, b, t1);          // (1+a)(1+b)
    float bm = b - 1.0f;
    float num = __builtin_fmaf(L2E2 * bm, t3, cs * t2);
    cs = num * __builtin_amdgcn_rcpf(t2 * t3);
    float e = __builtin_amdgcn_exp2f(cs);
    float t4 = 1.0f + d;
    float t5 = __builtin_fmaf(t4, e, t4);          // (1+d)(1+e)
    return (e - 1.0f) * __builtin_amdgcn_rcpf(t5);
}

__global__ __launch_bounds__(NT, 1) void lstm_fused(
    const float* __restrict__ x,
    const float* __restrict__ Wih0, const float* __restrict__ Whh0,
    const float* __restrict__ bih0, const float* __restrict__ bhh0,
    const float* __restrict__ Wih1, const float* __restrict__ Whh1,
    const float* __restrict__ bih1, const float* __restrict__ bhh1,
    float* __restrict__ h2last)
{
    // LDS: 64 + 8 + 8 + 2 = 82 KB
    __shared__ __align__(16) f16 whh1lds[8][4][2][64][8];  // [wg][gate][kt-2][lane][e]
    __shared__ __align__(16) f16 h1f[2][4][64][8];         // [buf][kt][lane][e] B-frag
    __shared__ __align__(16) f16 h2f[2][4][64][8];
    __shared__ __align__(16) f16 xf[2][64][8];             // x_aug (K=16: 14 x, 0, 1.0)

    const int tid = threadIdx.x;
    const int lane = tid & 63;
    const int wv = tid >> 6;          // wave 0..7 == j-group for BOTH layers
    const int n = lane & 15;          // batch column (valid < NB) / A-row index
    const int q = lane >> 4;          // quad -> rows q*4+r
    const int b0 = blockIdx.x * NB;

    // ---- zero state buffers: h1f,h2f = 4096 dwords total; xf = 512 dwords ----
    {
        unsigned int* z1 = (unsigned int*)h1f;
        unsigned int* z2 = (unsigned int*)h2f;
#pragma unroll
        for (int i = 0; i < 4; ++i) {
            z1[tid + i * 512] = 0u;
            z2[tid + i * 512] = 0u;
        }
        ((unsigned int*)xf)[tid] = 0u;
    }
    __syncthreads();

    // ---- x_aug constants (k==15 -> 1.0 in BOTH buffers) + stage x(0) into xf[0] ----
    if (tid < NB) {
        xf[0][tid + 16][7] = (f16)1.0f;
        xf[1][tid + 16][7] = (f16)1.0f;
    }
    if (tid < 64) {
        int nn_ = tid & 15, kq = tid >> 4;
        if (nn_ < NB && kq < 2) {
            half8 v;
#pragma unroll
            for (int e = 0; e < 8; ++e) {
                int k = kq * 8 + e;
                v[e] = (k < D_) ? (f16)x[(size_t)(b0 + nn_) * T_ * D_ + k]
                                : (k == 15 ? (f16)1.0f : (f16)0.0f);
            }
            *(half8*)&xf[0][tid][0] = v;
        }
    }

    // incremental x-prefetch pointer (valid only for threads < NB*D_)
    const float* xpp = x + (size_t)(b0 + (tid & 3)) * T_ * D_ + D_ + (tid >> 2);

    // ---- per-wave weights: layer-0 j-group wv AND layer-1 j-group wv ----
    const int wg = wv;
    half8 aWhh0[4][4], aWih0[4];      // layer-0: all in regs
    half8 aWih1[4][4], aWhh1r[4][2];  // layer-1: Wih1 + Whh1 kt0-1 regs; kt2-3 LDS
    f16x2 b1p[4][2];
#pragma unroll
    for (int g = 0; g < 4; ++g) {
        const float gs = (g == 2) ? L2E2 : L2E;   // g-gate rows pre-scaled 2x
        const int gr = g * 128 + wg * 16 + n;
#pragma unroll
        for (int kt = 0; kt < 4; ++kt)
            aWhh0[g][kt] = ldfrag_s(Whh0 + (size_t)gr * H_ + kt * 32 + q * 8, gs);
        half8 w0;
#pragma unroll
        for (int e = 0; e < 8; ++e) {
            int k = q * 8 + e;
            if (k < D_)       w0[e] = (f16)(Wih0[(size_t)gr * D_ + k] * gs);
            else if (k == 15) w0[e] = (f16)((bih0[gr] + bhh0[gr]) * gs);
            else              w0[e] = (f16)0.0f;
        }
        aWih0[g] = w0;
#pragma unroll
        for (int kt = 0; kt < 4; ++kt) {
            aWih1[g][kt] = ldfrag_s(Wih1 + (size_t)gr * H_ + kt * 32 + q * 8, gs);
            half8 wf = ldfrag_s(Whh1 + (size_t)gr * H_ + kt * 32 + q * 8, gs);
            if (kt < 2) aWhh1r[g][kt] = wf;
            else        *(half8*)&whh1lds[wg][g][kt - 2][lane][0] = wf;
        }
        const int gb = g * 128 + wg * 16 + q * 4;
        f16x2 p0, p1;
        p0[0] = (f16)((bih1[gb]     + bhh1[gb])     * gs);
        p0[1] = (f16)((bih1[gb + 1] + bhh1[gb + 1]) * gs);
        p1[0] = (f16)((bih1[gb + 2] + bhh1[gb + 2]) * gs);
        p1[1] = (f16)((bih1[gb + 3] + bhh1[gb + 3]) * gs);
        b1p[g][0] = p0;
        b1p[g][1] = p1;
    }

    floatx4 cs1 = {0.f, 0.f, 0.f, 0.f};   // layer-0 cell state, pre-scaled by 2*log2e
    floatx4 cs2 = {0.f, 0.f, 0.f, 0.f};   // layer-1 cell state, pre-scaled
    __syncthreads();

    // phase p: layer-0 computes h1(p) [p<T], layer-1 computes h2(p-1) [p>=1]
    for (int p = 0; p <= T_; ++p) {
        const int cur = p & 1, nxt = cur ^ 1;
        const bool doA = (p < T_);
        const bool doB = (p >= 1);

        float xp = 0.0f;
        if (tid < NB * D_ && (p + 1) < T_) xp = *xpp;

        // ---- top-of-phase fragment prefetch: 9 back-to-back ds_read_b128 ----
        // (buffers are valid/zero-initialized; unconditional loads keep the
        //  stream branch-free -- the MFMA clusters below stay guarded)
        half8 bx = *(const half8*)&xf[cur][lane][0];
        half8 bh1[4], bh2[4];
#pragma unroll
        for (int kt = 0; kt < 4; ++kt) bh1[kt] = *(const half8*)&h1f[cur][kt][lane][0];
#pragma unroll
        for (int kt = 0; kt < 4; ++kt) bh2[kt] = *(const half8*)&h2f[cur][kt][lane][0];

        floatx4 C0[4], C1[4];
#pragma unroll
        for (int g = 0; g < 4; ++g) {
            C0[g] = floatx4{0.f, 0.f, 0.f, 0.f};
            C1[g] = floatx4{0.f, 0.f, 0.f, 0.f};
        }

        if (doA) {
#pragma unroll
            for (int g = 0; g < 4; ++g) C0[g] = MFMA(aWih0[g], bx, C0[g]);
            // shared h1f fragments feed layer-0 recurrence...
#pragma unroll
            for (int kt = 0; kt < 4; ++kt)
#pragma unroll
                for (int g = 0; g < 4; ++g) C0[g] = MFMA(aWhh0[g][kt], bh1[kt], C0[g]);
        }
        if (doB) {
            // ...and the SAME h1f fragments feed layer-1 input
#pragma unroll
            for (int kt = 0; kt < 4; ++kt)
#pragma unroll
                for (int g = 0; g < 4; ++g) C1[g] = MFMA(aWih1[g][kt], bh1[kt], C1[g]);
#pragma unroll
            for (int kt = 0; kt < 2; ++kt)
#pragma unroll
                for (int g = 0; g < 4; ++g) C1[g] = MFMA(aWhh1r[g][kt], bh2[kt], C1[g]);
#pragma unroll
            for (int kt = 2; kt < 4; ++kt) {
#pragma unroll
                for (int g = 0; g < 4; ++g) {
                    half8 aw = *(const half8*)&whh1lds[wg][g][kt - 2][lane][0];
                    C1[g] = MFMA(aw, bh2[kt], C1[g]);
                }
            }
        }

        const int ktw = wg >> 1;
        const int qw = (wg & 1) * 2 + (q >> 1);
        const int eb = (q & 1) * 4;
        if (doA) {
            half4 hp;
#pragma unroll
            for (int r = 0; r < 4; ++r) {
                float c = cs1[r];
                hp[r] = (f16)cellP(C0[0][r], C0[1][r], C0[2][r], C0[3][r], c);
                cs1[r] = c;
            }
            if (n < NB) *(half4*)&h1f[nxt][ktw][n + 16 * qw][eb] = hp;
        }
        if (doB) {
            half4 hp;
            floatx4 hv;
#pragma unroll
            for (int r = 0; r < 4; ++r) {
                float pi = C1[0][r] + (float)b1p[0][r >> 1][r & 1];
                float pf = C1[1][r] + (float)b1p[1][r >> 1][r & 1];
                float pg = C1[2][r] + (float)b1p[2][r >> 1][r & 1];
                float po = C1[3][r] + (float)b1p[3][r >> 1][r & 1];
                float c = cs2[r];
                hv[r] = cellP(pi, pf, pg, po, c);
                cs2[r] = c;
                hp[r] = (f16)hv[r];
            }
            if (n < NB) {
                *(half4*)&h2f[nxt][ktw][n + 16 * qw][eb] = hp;
                if (p == T_) {
#pragma unroll
                    for (int r = 0; r < 4; ++r)
                        h2last[(size_t)(b0 + n) * H_ + wg * 16 + q * 4 + r] = hv[r];
                }
            }
        }
        if (tid < NB * D_ && (p + 1) < T_) {
            int k = tid >> 2;
            xf[nxt][(tid & 3) + 16 * (k >> 3)][k & 7] = (f16)xp;
            xpp += D_;
        }
        __syncthreads();
    }
}

// batch-norm statistics over the batch dim: 1 block, 1024 threads
__global__ void bn_stats(const float* __restrict__ h2last, float* __restrict__ stats)
{
    __shared__ float red[2][8][128];
    const int tid = threadIdx.x;
    const int j = tid & 127, bs = tid >> 7;
    float s = 0.0f, ss = 0.0f;
    for (int bb = 0; bb < 128; ++bb) {
        float v = h2last[(size_t)(bb * 8 + bs) * H_ + j];
        s += v;
        ss += v * v;
    }
    red[0][bs][j] = s;
    red[1][bs][j] = ss;
    __syncthreads();
    if (tid < 128) {
        float S = 0.0f, SS = 0.0f;
#pragma unroll
        for (int k = 0; k < 8; ++k) { S += red[0][k][tid]; SS += red[1][k][tid]; }
        float mu = S * (1.0f / 1024.0f);
        float var = SS * (1.0f / 1024.0f) - mu * mu;
        stats[tid] = mu;
        stats[128 + tid] = __builtin_amdgcn_rsqf(var + 1e-5f);
    }
}

// normalize + MLP head: 8 blocks x 128 threads, one batch element per thread
__global__ void bn_mlp(const float* __restrict__ h2last, const float* __restrict__ stats,
                       const float* __restrict__ gamma, const float* __restrict__ beta,
                       const float* __restrict__ W1, const float* __restrict__ b1,
                       const float* __restrict__ W2, const float* __restrict__ b2,
                       float* __restrict__ out)
{
    __shared__ float W1T[128][33];
    __shared__ float mus[128], isds[128], gs[128], bts[128], w2s[32];
    const int tid = threadIdx.x;
    const int b = blockIdx.x * 128 + tid;

    for (int i = tid; i < 4096; i += 128) {
        int k = i >> 7, j = i & 127;
        W1T[j][k] = W1[i];
    }
    mus[tid] = stats[tid];
    isds[tid] = stats[128 + tid];
    gs[tid] = gamma[tid];
    bts[tid] = beta[tid];
    if (tid < 32) w2s[tid] = W2[tid];
    __syncthreads();

    float z[32];
#pragma unroll
    for (int k = 0; k < 32; ++k) z[k] = b1[k];

    for (int j = 0; j < 128; ++j) {
        float nv = (h2last[(size_t)b * H_ + j] - mus[j]) * isds[j] * gs[j] + bts[j];
#pragma unroll
        for (int k = 0; k < 32; ++k) z[k] += W1T[j][k] * nv;
    }
    float o = b2[0];
#pragma unroll
    for (int k = 0; k < 32; ++k) o += w2s[k] * fmaxf(z[k], 0.0f);
    out[b] = o;
}

extern "C" void kernel_launch(void* const* d_in, const int* in_sizes, int n_in,
                              void* d_out, int out_size, void* d_ws, size_t ws_size,
                              hipStream_t stream)
{
    const float* x    = (const float*)d_in[0];
    const float* Wih0 = (const float*)d_in[1];
    const float* Whh0 = (const float*)d_in[2];
    const float* bih0 = (const float*)d_in[3];
    const float* bhh0 = (const float*)d_in[4];
    const float* Wih1 = (const float*)d_in[5];
    const float* Whh1 = (const float*)d_in[6];
    const float* bih1 = (const float*)d_in[7];
    const float* bhh1 = (const float*)d_in[8];
    const float* gamma = (const float*)d_in[9];
    const float* beta  = (const float*)d_in[10];
    const float* W1 = (const float*)d_in[11];
    const float* b1 = (const float*)d_in[12];
    const float* W2 = (const float*)d_in[13];
    const float* b2 = (const float*)d_in[14];

    float* h2last = (float*)d_ws;              // 1024*128 floats = 512 KB
    float* stats  = h2last + (size_t)B_ * H_;  // 256 floats
    float* out = (float*)d_out;

    hipLaunchKernelGGL(lstm_fused, dim3(B_ / NB), dim3(NT), 0, stream,
                       x, Wih0, Whh0, bih0, bhh0, Wih1, Whh1, bih1, bhh1, h2last);
    hipLaunchKernelGGL(bn_stats, dim3(1), dim3(1024), 0, stream, h2last, stats);
    hipLaunchKernelGGL(bn_mlp, dim3(8), dim3(128), 0, stream,
                       h2last, stats, gamma, beta, W1, b1, W2, b2, out);
}

// Round 13
// 912.636 us; speedup vs baseline: 1.4406x; 1.4406x over previous
//
#include <hip/hip_runtime.h>

// ForexLSTM: 2-layer LSTM (B=1024, T=512, D=14, H=128) + batchnorm-over-batch + MLP(128->32->1)
//
// Round 23: RESUBMIT of R22 verbatim -- the R22 bench died with "MI355X container
// failed twice" (infra; no compile/test output; same signature as R5/R9, both of which
// re-ran cleanly as R16/R20). Re-running rather than stacking an unmeasured change.
//
// R22 = cellP redistribution via DPP row-shifts, on the R12 base (the only no-scratch
// shape: VGPR 256, WRITE 0.5MB, 964.7us). R21's fragment hoist flipped the allocator
// back into the 128-clamp (+90MB scratch, 1314us) -- reverted entirely. Transport
// history for the one-cellP-per-lane win (VALUBusy 38->23, R14-proven): LDS cred ->
// clamped; bpermute -> clamped + LDS crossbar (71M conflicts); DPP is the remaining
// transport with NO memory pipe and NO barriers:
//   - dest lane l (cell j=q*4+rsel, col=l&3; rsel=(l>>2)&3) needs C[g][rsel] from lane
//     l-4*rsel, same 16-lane DPP row -> v_mov_dpp row_shr:4/8/12 on elements 1-3 of
//     each accumulator + 3 cndmask selects per gate. 24 full-rate VALU ops per layer.
//   - All 64 lanes now compute useful cells (R12 wasted 48/64): per-lane trans 56->14.
//     Results bit-identical to R12 (same per-cell arithmetic, different lane).
//   - Stores become per-lane ds_write_b16 scatters (same data, one inst, <=4-way
//     write aliasing). cs state 8 regs -> 2. No setprio, no sched_barrier, no asm.
//   - Everything else R12-exact: wave-role merge, inline fragment reads in the kt
//     loops (R21 hoist reverted), Whh1 kt0-1 regs / kt2-3 LDS (82 KB), fused-
//     reciprocal cellP (5 exp2 + 2 rcp), incremental x prefetch, launch_bounds(NT,1).

#define B_ 1024
#define T_ 512
#define D_ 14
#define H_ 128
#define NB 4
#define NT 512

#define L2E 1.44269504088896f
#define L2E2 2.88539008177793f

typedef _Float16 f16;
typedef _Float16 half4 __attribute__((ext_vector_type(4)));
typedef _Float16 half8 __attribute__((ext_vector_type(8)));
typedef float floatx4 __attribute__((ext_vector_type(4)));

__device__ __forceinline__ half8 ldfrag_s(const float* __restrict__ p, float s) {
    half8 r;
#pragma unroll
    for (int j = 0; j < 8; ++j) r[j] = (f16)(p[j] * s);
    return r;
}

#define MFMA(a, b, c) __builtin_amdgcn_mfma_f32_16x16x32_f16((a), (b), (c), 0, 0, 0)

// Fused LSTM cell epilogue on pre-scaled gates:
//   pi,pf,po = y*log2e ; pg = 2x*log2e ; cs = 2*log2e*c (scaled cell state, updated).
// Returns h in true units. 5 exp2 + 2 rcp.
__device__ __forceinline__ float cellP(float pi, float pf, float pg, float po, float& cs)
{
    float a = __builtin_amdgcn_exp2f(-pi);
    float u = __builtin_amdgcn_exp2f(-pf);
    float b = __builtin_amdgcn_exp2f(pg);
    float d = __builtin_amdgcn_exp2f(-po);
    float t1 = 1.0f + a;
    float t3 = 1.0f + u;
    float t2 = __builtin_fmaf(t1, b, t1);          // (1+a)(1+b)
    float bm = b - 1.0f;
    float num = __builtin_fmaf(L2E2 * bm, t3, cs * t2);
    cs = num * __builtin_amdgcn_rcpf(t2 * t3);
    float e = __builtin_amdgcn_exp2f(cs);
    float t4 = 1.0f + d;
    float t5 = __builtin_fmaf(t4, e, t4);          // (1+d)(1+e)
    return (e - 1.0f) * __builtin_amdgcn_rcpf(t5);
}

// gather this lane's gate value from the MFMA accumulator via DPP row-shifts:
// dest lane l needs element rsel=(l>>2)&3 from source lane l-4*rsel (same DPP row).
__device__ __forceinline__ float dpp_gate(int rsel, floatx4 Cg)
{
    // row_shr:4 = 0x114, row_shr:8 = 0x118, row_shr:12 = 0x11C
    float s1 = __int_as_float(__builtin_amdgcn_update_dpp(
        0, __float_as_int(Cg[1]), 0x114, 0xF, 0xF, true));
    float s2 = __int_as_float(__builtin_amdgcn_update_dpp(
        0, __float_as_int(Cg[2]), 0x118, 0xF, 0xF, true));
    float s3 = __int_as_float(__builtin_amdgcn_update_dpp(
        0, __float_as_int(Cg[3]), 0x11C, 0xF, 0xF, true));
    return rsel == 0 ? Cg[0] : (rsel == 1 ? s1 : (rsel == 2 ? s2 : s3));
}

__global__ __launch_bounds__(NT, 1) void lstm_fused(
    const float* __restrict__ x,
    const float* __restrict__ Wih0, const float* __restrict__ Whh0,
    const float* __restrict__ bih0, const float* __restrict__ bhh0,
    const float* __restrict__ Wih1, const float* __restrict__ Whh1,
    const float* __restrict__ bih1, const float* __restrict__ bhh1,
    float* __restrict__ h2last)
{
    // LDS: 64 + 8 + 8 + 2 = 82 KB
    __shared__ __align__(16) f16 whh1lds[8][4][2][64][8];  // [wg][gate][kt-2][lane][e]
    __shared__ __align__(16) f16 h1f[2][4][64][8];         // [buf][kt][lane][e] B-frag
    __shared__ __align__(16) f16 h2f[2][4][64][8];
    __shared__ __align__(16) f16 xf[2][64][8];             // x_aug (K=16: 14 x, 0, 1.0)

    const int tid = threadIdx.x;
    const int lane = tid & 63;
    const int wv = tid >> 6;          // wave 0..7 == j-group for BOTH layers
    const int n = lane & 15;          // batch column (valid < NB) / A-row index
    const int q = lane >> 4;          // quad -> rows q*4+r
    const int b0 = blockIdx.x * NB;

    // ---- zero state buffers: h1f,h2f = 4096 dwords total; xf = 512 dwords ----
    {
        unsigned int* z1 = (unsigned int*)h1f;
        unsigned int* z2 = (unsigned int*)h2f;
#pragma unroll
        for (int i = 0; i < 4; ++i) {
            z1[tid + i * 512] = 0u;
            z2[tid + i * 512] = 0u;
        }
        ((unsigned int*)xf)[tid] = 0u;
    }
    __syncthreads();

    // ---- x_aug constants (k==15 -> 1.0 in BOTH buffers) + stage x(0) into xf[0] ----
    if (tid < NB) {
        xf[0][tid + 16][7] = (f16)1.0f;
        xf[1][tid + 16][7] = (f16)1.0f;
    }
    if (tid < 64) {
        int nn_ = tid & 15, kq = tid >> 4;
        if (nn_ < NB && kq < 2) {
            half8 v;
#pragma unroll
            for (int e = 0; e < 8; ++e) {
                int k = kq * 8 + e;
                v[e] = (k < D_) ? (f16)x[(size_t)(b0 + nn_) * T_ * D_ + k]
                                : (k == 15 ? (f16)1.0f : (f16)0.0f);
            }
            *(half8*)&xf[0][tid][0] = v;
        }
    }

    // incremental x-prefetch pointer (valid only for threads < NB*D_)
    const float* xpp = x + (size_t)(b0 + (tid & 3)) * T_ * D_ + D_ + (tid >> 2);

    // ---- per-wave weights: layer-0 j-group wv AND layer-1 j-group wv ----
    const int wg = wv;
    half8 aWhh0[4][4], aWih0[4];      // layer-0: all in regs
    half8 aWih1[4][4], aWhh1r[4][2];  // layer-1: Wih1 + Whh1 kt0-1 regs; kt2-3 LDS
#pragma unroll
    for (int g = 0; g < 4; ++g) {
        const float gs = (g == 2) ? L2E2 : L2E;   // g-gate rows pre-scaled 2x
        const int gr = g * 128 + wg * 16 + n;
#pragma unroll
        for (int kt = 0; kt < 4; ++kt)
            aWhh0[g][kt] = ldfrag_s(Whh0 + (size_t)gr * H_ + kt * 32 + q * 8, gs);
        half8 w0;
#pragma unroll
        for (int e = 0; e < 8; ++e) {
            int k = q * 8 + e;
            if (k < D_)       w0[e] = (f16)(Wih0[(size_t)gr * D_ + k] * gs);
            else if (k == 15) w0[e] = (f16)((bih0[gr] + bhh0[gr]) * gs);
            else              w0[e] = (f16)0.0f;
        }
        aWih0[g] = w0;
#pragma unroll
        for (int kt = 0; kt < 4; ++kt) {
            aWih1[g][kt] = ldfrag_s(Wih1 + (size_t)gr * H_ + kt * 32 + q * 8, gs);
            half8 wf = ldfrag_s(Whh1 + (size_t)gr * H_ + kt * 32 + q * 8, gs);
            if (kt < 2) aWhh1r[g][kt] = wf;
            else        *(half8*)&whh1lds[wg][g][kt - 2][lane][0] = wf;
        }
    }

    // ---- per-lane (dest-cell) constants for the DPP-redistributed epilogue ----
    const int colp = lane & 3;        // dest batch column (0..3, all valid)
    const int rsel = (lane >> 2) & 3; // source accumulator element / row-within-quad
    const int jj2 = q * 4 + rsel;     // dest cell row j within the wave's 16-row group
    const int ktD = wg >> 1;
    const int rowD = colp + 16 * ((wg & 1) * 2 + (q >> 1));
    const int eD = (q & 1) * 4 + rsel;
    float bias1v[4];
#pragma unroll
    for (int g = 0; g < 4; ++g) {
        const float gs = (g == 2) ? L2E2 : L2E;
        const int gb = g * 128 + wg * 16 + jj2;
        bias1v[g] = (bih1[gb] + bhh1[gb]) * gs;
    }

    float cs1 = 0.0f;   // layer-0 cell state for cell (jj2, colp), pre-scaled 2*log2e
    float cs2 = 0.0f;   // layer-1 cell state
    __syncthreads();

    // phase p: layer-0 computes h1(p) [p<T], layer-1 computes h2(p-1) [p>=1]
    for (int p = 0; p <= T_; ++p) {
        const int cur = p & 1, nxt = cur ^ 1;
        const bool doA = (p < T_);
        const bool doB = (p >= 1);

        float xp = 0.0f;
        if (tid < NB * D_ && (p + 1) < T_) xp = *xpp;

        floatx4 C0[4], C1[4];
#pragma unroll
        for (int g = 0; g < 4; ++g) {
            C0[g] = floatx4{0.f, 0.f, 0.f, 0.f};
            C1[g] = floatx4{0.f, 0.f, 0.f, 0.f};
        }

        if (doA) {
            half8 bx = *(const half8*)&xf[cur][lane][0];
#pragma unroll
            for (int g = 0; g < 4; ++g) C0[g] = MFMA(aWih0[g], bx, C0[g]);
        }
        // shared h1f fragments: feed layer-0 recurrence AND layer-1 input
#pragma unroll
        for (int kt = 0; kt < 4; ++kt) {
            half8 bh = *(const half8*)&h1f[cur][kt][lane][0];
            if (doA) {
#pragma unroll
                for (int g = 0; g < 4; ++g) C0[g] = MFMA(aWhh0[g][kt], bh, C0[g]);
            }
            if (doB) {
#pragma unroll
                for (int g = 0; g < 4; ++g) C1[g] = MFMA(aWih1[g][kt], bh, C1[g]);
            }
        }
        if (doB) {
#pragma unroll
            for (int kt = 0; kt < 2; ++kt) {
                half8 bh = *(const half8*)&h2f[cur][kt][lane][0];
#pragma unroll
                for (int g = 0; g < 4; ++g) C1[g] = MFMA(aWhh1r[g][kt], bh, C1[g]);
            }
#pragma unroll
            for (int kt = 2; kt < 4; ++kt) {
                half8 bh = *(const half8*)&h2f[cur][kt][lane][0];
#pragma unroll
                for (int g = 0; g < 4; ++g) {
                    half8 aw = *(const half8*)&whh1lds[wg][g][kt - 2][lane][0];
                    C1[g] = MFMA(aw, bh, C1[g]);
                }
            }
        }

        // ---- layer-0 epilogue: DPP-gather 4 gates, one cellP per lane ----
        if (doA) {
            float g0 = dpp_gate(rsel, C0[0]);
            float g1 = dpp_gate(rsel, C0[1]);
            float g2 = dpp_gate(rsel, C0[2]);
            float g3 = dpp_gate(rsel, C0[3]);
            float h0 = cellP(g0, g1, g2, g3, cs1);
            h1f[nxt][ktD][rowD][eD] = (f16)h0;
        }

        // ---- layer-1 epilogue ----
        if (doB) {
            float g0 = dpp_gate(rsel, C1[0]) + bias1v[0];
            float g1 = dpp_gate(rsel, C1[1]) + bias1v[1];
            float g2 = dpp_gate(rsel, C1[2]) + bias1v[2];
            float g3 = dpp_gate(rsel, C1[3]) + bias1v[3];
            float hv = cellP(g0, g1, g2, g3, cs2);
            h2f[nxt][ktD][rowD][eD] = (f16)hv;
            if (p == T_)
                h2last[(size_t)(b0 + colp) * H_ + wg * 16 + jj2] = hv;
        }

        if (tid < NB * D_ && (p + 1) < T_) {
            int k = tid >> 2;
            xf[nxt][(tid & 3) + 16 * (k >> 3)][k & 7] = (f16)xp;
            xpp += D_;
        }
        __syncthreads();
    }
}

// batch-norm statistics over the batch dim: 1 block, 1024 threads
__global__ void bn_stats(const float* __restrict__ h2last, float* __restrict__ stats)
{
    __shared__ float red[2][8][128];
    const int tid = threadIdx.x;
    const int j = tid & 127, bs = tid >> 7;
    float s = 0.0f, ss = 0.0f;
    for (int bb = 0; bb < 128; ++bb) {
        float v = h2last[(size_t)(bb * 8 + bs) * H_ + j];
        s += v;
        ss += v * v;
    }
    red[0][bs][j] = s;
    red[1][bs][j] = ss;
    __syncthreads();
    if (tid < 128) {
        float S = 0.0f, SS = 0.0f;
#pragma unroll
        for (int k = 0; k < 8; ++k) { S += red[0][k][tid]; SS += red[1][k][tid]; }
        float mu = S * (1.0f / 1024.0f);
        float var = SS * (1.0f / 1024.0f) - mu * mu;
        stats[tid] = mu;
        stats[128 + tid] = __builtin_amdgcn_rsqf(var + 1e-5f);
    }
}

// normalize + MLP head: 8 blocks x 128 threads, one batch element per thread
__global__ void bn_mlp(const float* __restrict__ h2last, const float* __restrict__ stats,
                       const float* __restrict__ gamma, const float* __restrict__ beta,
                       const float* __restrict__ W1, const float* __restrict__ b1,
                       const float* __restrict__ W2, const float* __restrict__ b2,
                       float* __restrict__ out)
{
    __shared__ float W1T[128][33];
    __shared__ float mus[128], isds[128], gs[128], bts[128], w2s[32];
    const int tid = threadIdx.x;
    const int b = blockIdx.x * 128 + tid;

    for (int i = tid; i < 4096; i += 128) {
        int k = i >> 7, j = i & 127;
        W1T[j][k] = W1[i];
    }
    mus[tid] = stats[tid];
    isds[tid] = stats[128 + tid];
    gs[tid] = gamma[tid];
    bts[tid] = beta[tid];
    if (tid < 32) w2s[tid] = W2[tid];
    __syncthreads();

    float z[32];
#pragma unroll
    for (int k = 0; k < 32; ++k) z[k] = b1[k];

    for (int j = 0; j < 128; ++j) {
        float nv = (h2last[(size_t)b * H_ + j] - mus[j]) * isds[j] * gs[j] + bts[j];
#pragma unroll
        for (int k = 0; k < 32; ++k) z[k] += W1T[j][k] * nv;
    }
    float o = b2[0];
#pragma unroll
    for (int k = 0; k < 32; ++k) o += w2s[k] * fmaxf(z[k], 0.0f);
    out[b] = o;
}

extern "C" void kernel_launch(void* const* d_in, const int* in_sizes, int n_in,
                              void* d_out, int out_size, void* d_ws, size_t ws_size,
                              hipStream_t stream)
{
    const float* x    = (const float*)d_in[0];
    const float* Wih0 = (const float*)d_in[1];
    const float* Whh0 = (const float*)d_in[2];
    const float* bih0 = (const float*)d_in[3];
    const float* bhh0 = (const float*)d_in[4];
    const float* Wih1 = (const float*)d_in[5];
    const float* Whh1 = (const float*)d_in[6];
    const float* bih1 = (const float*)d_in[7];
    const float* bhh1 = (const float*)d_in[8];
    const float* gamma = (const float*)d_in[9];
    const float* beta  = (const float*)d_in[10];
    const float* W1 = (const float*)d_in[11];
    const float* b1 = (const float*)d_in[12];
    const float* W2 = (const float*)d_in[13];
    const float* b2 = (const float*)d_in[14];

    float* h2last = (float*)d_ws;              // 1024*128 floats = 512 KB
    float* stats  = h2last + (size_t)B_ * H_;  // 256 floats
    float* out = (float*)d_out;

    hipLaunchKernelGGL(lstm_fused, dim3(B_ / NB), dim3(NT), 0, stream,
                       x, Wih0, Whh0, bih0, bhh0, Wih1, Whh1, bih1, bhh1, h2last);
    hipLaunchKernelGGL(bn_stats, dim3(1), dim3(1024), 0, stream, h2last, stats);
    hipLaunchKernelGGL(bn_mlp, dim3(8), dim3(128), 0, stream,
                       h2last, stats, gamma, beta, W1, b1, W2, b2, out);
}